// Round 8
// baseline (221.411 us; speedup 1.0000x reference)
//
#include <hip/hip_runtime.h>
#include <stdint.h>

#define NROWS 65536
#define HD 1024

typedef __attribute__((ext_vector_type(8))) short bf16x8;   // 8 bf16 in 4 VGPRs
typedef __attribute__((ext_vector_type(16))) float f32x16;  // MFMA 32x32 accumulator

typedef __attribute__((address_space(1))) const unsigned int* gas_ptr;
typedef __attribute__((address_space(3))) unsigned int* las_ptr;

__device__ __forceinline__ unsigned short f2bf(float f) {
  union { float f; uint32_t u; } v; v.f = f;
  uint32_t u = v.u;
  return (unsigned short)((u + 0x7fffu + ((u >> 16) & 1u)) >> 16);  // RNE
}

__device__ __forceinline__ void gl16(const void* g, void* l) {
  __builtin_amdgcn_global_load_lds((gas_ptr)g, (las_ptr)l, 16, 0, 0);
}

// ---------------- prep: W2 fp32 -> bf16, swizzled granules (R5 layout) ----------------
// W2bf[c][k]; 16B granule g stored at (g&~3) | ((g&3) ^ ((c>>1)&3)).
__global__ void k_w2bf(const float* __restrict__ W2, unsigned short* __restrict__ W2bf) {
  int i = blockIdx.x * 256 + threadIdx.x;   // 131072 threads, 1 granule each
  int c = i >> 7, g = i & 127;
  const float4* s4 = (const float4*)(W2 + (size_t)c * HD + g * 8);
  float4 a = s4[0], b = s4[1];
  uint4 pk;
  pk.x = (uint32_t)f2bf(a.x) | ((uint32_t)f2bf(a.y) << 16);
  pk.y = (uint32_t)f2bf(a.z) | ((uint32_t)f2bf(a.w) << 16);
  pk.z = (uint32_t)f2bf(b.x) | ((uint32_t)f2bf(b.y) << 16);
  pk.w = (uint32_t)f2bf(b.z) | ((uint32_t)f2bf(b.w) << 16);
  int gs = (g & 124) | ((g & 3) ^ ((c >> 1) & 3));
  *(uint4*)(W2bf + (size_t)c * HD + gs * 8) = pk;
}

// ---------------- layer 1 (R5): h bf16 [65536][1024], granule swizzle (g&3)^((row>>1)&3) ----------------
__global__ __launch_bounds__(512) void k_layer1(
    const float* __restrict__ x, const float* __restrict__ W1,
    const float* __restrict__ b1, const float* __restrict__ Wmeta,
    const float* __restrict__ bmeta, unsigned short* __restrict__ h) {
  __shared__ float xs[128 * 12];
  int r0 = blockIdx.x * 128;
  int t = threadIdx.x;
  int j0 = t * 2;
  float w1a = W1[j0], w1b = W1[j0 + 1];
  float b1a = b1[j0], b1b = b1[j0 + 1];
  float wma[10], wmb[10], bma[10], bmb[10];
#pragma unroll
  for (int e = 0; e < 10; e++) {
    float2 wmv = *(const float2*)(Wmeta + e * HD + j0);
    float2 bmv = *(const float2*)(bmeta + e * HD + j0);
    wma[e] = wmv.x; wmb[e] = wmv.y; bma[e] = bmv.x; bmb[e] = bmv.y;
  }
  for (int i = t; i < 128 * 12; i += 512) xs[i] = x[(size_t)r0 * 12 + i];
  __syncthreads();
  int g = j0 >> 3;
  for (int r = 0; r < 128; r++) {
    const float* xr = xs + r * 12;
    float delta = xr[10], phi = xr[11];
    float s1a = 0.f, s1b = 0.f, s2a = 0.f, s2b = 0.f;
#pragma unroll
    for (int e = 0; e < 10; e++) {
      float oh = xr[e];
      s1a = fmaf(oh, wma[e], s1a);
      s1b = fmaf(oh, wmb[e], s1b);
      s2a = fmaf(oh, bma[e], s2a);
      s2b = fmaf(oh, bmb[e], s2b);
    }
    float pa = fmaf(delta, w1a, b1a) + fmaf(phi, s1a, s2a);
    float pb = fmaf(delta, w1b, b1b) + fmaf(phi, s1b, s2b);
    pa = fmaxf(pa, 0.f); pb = fmaxf(pb, 0.f);
    uint32_t pk = (uint32_t)f2bf(pa) | ((uint32_t)f2bf(pb) << 16);
    int rr = r0 + r;
    int gs = (g & 124) | ((g & 3) ^ ((rr >> 1) & 3));
    *(uint32_t*)(h + (size_t)rr * HD + gs * 8 + (j0 & 7)) = pk;
  }
}

// ---------------- layers 2+3: R5 structure, occupancy raised to 5 blocks/CU ----------------
// grid 4096 (XCD-swizzled) = 512 rt x 8 ct; 256 threads = 4 waves (2x2), wave tile 64x64
// = 2x2 of 32x32x16 bf16 MFMA (acc 64 VGPR). Single 32 KiB LDS buffer, 2 syncs/tile.
// LDS = exactly 32768 B -> 5 blocks/CU (160 KiB pool); latency hidden by cross-block TLP.
__global__ __launch_bounds__(256, 5) void k_gemm(
    const unsigned short* __restrict__ h, const unsigned short* __restrict__ W2bf,
    const float* __restrict__ b2, const float* __restrict__ W3,
    float* __restrict__ partial) {
  __shared__ char lds[32768];   // A panels @0/8192, B panels @16384/24576; epilogue reuses 16.9 KB
  int tid = threadIdx.x;
  // XCD swizzle: 4096 blocks = 8 XCDs x 512; XCD k gets contiguous logical range.
  int b = (int)blockIdx.x;
  int bx = ((b & 7) << 9) | (b >> 3);
  int rt = bx >> 3, ct = bx & 7;   // 8 consecutive bx share rt -> A-panel L2 reuse
  size_t r0 = (size_t)rt * 128;
  int c0 = ct * 128;
  int w = tid >> 6, lane = tid & 63;
  int wm = w >> 1, wn = w & 1;
  int l31 = lane & 31, hi = lane >> 5;
  int sw = (l31 >> 1) & 3;   // granule swizzle key (row bases are multiples of 32)

  f32x16 acc[2][2];
#pragma unroll
  for (int rb = 0; rb < 2; rb++)
#pragma unroll
    for (int cb = 0; cb < 2; cb++)
#pragma unroll
      for (int i = 0; i < 16; i++) acc[rb][cb][i] = 0.f;

  int arow0 = (wm * 64 + 0  + l31) * 64;
  int arow1 = (wm * 64 + 32 + l31) * 64;
  int brow0 = (wn * 64 + 0  + l31) * 64;
  int brow1 = (wn * 64 + 32 + l31) * 64;

  for (int T = 0; T < 16; T++) {
    // stage tile T: A panels at 0/8192, B panels at 16384/24576; dest linear in s.
#pragma unroll
    for (int q = 0; q < 2; q++) {
      int s = tid + 256 * q;            // 0..511
      int row = s >> 2, g4 = s & 3;
      const unsigned short* hsrc = h    + (r0 + row) * (size_t)HD + T * 64 + g4 * 8;
      const unsigned short* wsrc = W2bf + (size_t)(c0 + row) * HD + T * 64 + g4 * 8;
      gl16(hsrc,      lds +         (size_t)s * 16);
      gl16(hsrc + 32, lds +  8192 + (size_t)s * 16);
      gl16(wsrc,      lds + 16384 + (size_t)s * 16);
      gl16(wsrc + 32, lds + 24576 + (size_t)s * 16);
    }
    __syncthreads();   // drains vmcnt: tile T landed; prior reads done before overwrite
#pragma unroll
    for (int p = 0; p < 2; p++) {
      const char* lA = lds + p * 8192;
      const char* lB = lds + 16384 + p * 8192;
#pragma unroll
      for (int kl = 0; kl < 2; kl++) {
        int slot = ((kl * 2 + hi) ^ sw) << 4;
        bf16x8 a0 = *(const bf16x8*)(lA + arow0 + slot);
        bf16x8 a1 = *(const bf16x8*)(lA + arow1 + slot);
        bf16x8 b0 = *(const bf16x8*)(lB + brow0 + slot);
        bf16x8 b1 = *(const bf16x8*)(lB + brow1 + slot);
        acc[0][0] = __builtin_amdgcn_mfma_f32_32x32x16_bf16(a0, b0, acc[0][0], 0, 0, 0);
        acc[0][1] = __builtin_amdgcn_mfma_f32_32x32x16_bf16(a0, b1, acc[0][1], 0, 0, 0);
        acc[1][0] = __builtin_amdgcn_mfma_f32_32x32x16_bf16(a1, b0, acc[1][0], 0, 0, 0);
        acc[1][1] = __builtin_amdgcn_mfma_f32_32x32x16_bf16(a1, b1, acc[1][1], 0, 0, 0);
      }
    }
    __syncthreads();
  }

  // ---- epilogue: v = relu(acc+b2); o = v x W3^T; 4 transpose-reduce passes (16.9 KB each) ----
  float b2c[2], w30[2], w31[2];
#pragma unroll
  for (int cb = 0; cb < 2; cb++) {
    int c = c0 + wn * 64 + cb * 32 + l31;
    b2c[cb] = b2[c];
    w30[cb] = W3[c];
    w31[cb] = W3[HD + c];
  }
  // per pass (rb,d): line = (wm*32+rowf)*2+wn in [0,128); float slot = line*33 + l31
  float* sF = (float*)lds;
#pragma unroll
  for (int rb = 0; rb < 2; rb++) {
#pragma unroll
    for (int d = 0; d < 2; d++) {
      __syncthreads();
#pragma unroll
      for (int reg = 0; reg < 16; reg++) {
        float v0 = fmaxf(acc[rb][0][reg] + b2c[0], 0.f);
        float v1 = fmaxf(acc[rb][1][reg] + b2c[1], 0.f);
        float o = (d == 0) ? fmaf(v0, w30[0], v1 * w30[1])
                           : fmaf(v0, w31[0], v1 * w31[1]);
        int rowf = (reg & 3) + 8 * (reg >> 2) + 4 * hi;   // verified C/D row map
        int line = (wm * 32 + rowf) * 2 + wn;
        sF[line * 33 + l31] = o;
      }
      __syncthreads();
      // reduce: 64 half-rows, 4 threads each (2 lines x 2 col-halves), then 2 shfls
      int h64 = tid >> 2, sub = tid & 3;
      int line0 = h64 * 2 + (sub >> 1);
      int j0 = (sub & 1) * 16;
      float s = 0.f;
#pragma unroll
      for (int j = 0; j < 16; j++) s += sF[line0 * 33 + j0 + j];
      s += __shfl_xor(s, 1);
      s += __shfl_xor(s, 2);
      if (sub == 0) {
        int grow = (h64 & 31) + (h64 >> 5) * 64 + rb * 32;   // undo line packing
        partial[(size_t)ct * (NROWS * 2) + (r0 + grow) * 2 + d] = s;
      }
    }
  }
}

// ---------------- final: out = b3 + sum over 8 col-tile partials ----------------
__global__ void k_reduce(const float* __restrict__ partial, const float* __restrict__ b3,
                         float* __restrict__ out) {
  int i = blockIdx.x * 256 + threadIdx.x;  // 131072
  float s = b3[i & 1];
#pragma unroll
  for (int ctt = 0; ctt < 8; ctt++) s += partial[(size_t)ctt * 131072 + i];
  out[i] = s;
}

extern "C" void kernel_launch(void* const* d_in, const int* in_sizes, int n_in,
                              void* d_out, int out_size, void* d_ws, size_t ws_size,
                              hipStream_t stream) {
  const float* x     = (const float*)d_in[0];
  const float* W1    = (const float*)d_in[1];
  const float* b1    = (const float*)d_in[2];
  const float* Wmeta = (const float*)d_in[3];
  const float* bmeta = (const float*)d_in[4];
  const float* W2    = (const float*)d_in[5];
  const float* b2    = (const float*)d_in[6];
  const float* W3    = (const float*)d_in[7];
  const float* b3    = (const float*)d_in[8];
  float* out = (float*)d_out;

  char* ws = (char*)d_ws;
  unsigned short* hbuf  = (unsigned short*)ws;                              // 128 MiB
  unsigned short* W2bf  = (unsigned short*)(ws + (size_t)NROWS * HD * 2);   // 2 MiB
  float* partial = (float*)(ws + (size_t)NROWS * HD * 2 + (size_t)HD * HD * 2);  // 4 MiB (8 slices)

  k_w2bf<<<512, 256, 0, stream>>>(W2, W2bf);
  k_layer1<<<512, 512, 0, stream>>>(x, W1, b1, Wmeta, bmeta, hbuf);
  k_gemm<<<4096, 256, 0, stream>>>(hbuf, W2bf, b2, W3, partial);
  k_reduce<<<512, 256, 0, stream>>>(partial, b3, out);
}